// Round 3
// baseline (57.735 us; speedup 1.0000x reference)
//
#include <hip/hip_runtime.h>

#define SEQ_LEN 131072
#define D_MODEL 512
#define M_SIZE  1000
#define BETA    0.5f

typedef float f32x4 __attribute__((ext_vector_type(4)));

// ---------------------------------------------------------------------------
// Transpose W_m [D_MODEL][M] -> W_mT [M][D_MODEL] so the per-row gather in the
// main kernel becomes contiguous float4 loads (2 MB, L2-resident).
// ---------------------------------------------------------------------------
__global__ void transpose_wm_kernel(const float* __restrict__ W_m,
                                    float* __restrict__ W_mT) {
    __shared__ float tile[32][33];  // +1 pad: no LDS bank conflicts
    const int bx = blockIdx.x;      // tile along M (cols of W_m)
    const int by = blockIdx.y;      // tile along D (rows of W_m)
    const int tx = threadIdx.x;     // 0..31
    const int ty = threadIdx.y;     // 0..7

    const int m = bx * 32 + tx;
    const int d0 = by * 32;
    for (int i = ty; i < 32; i += 8) {
        const int d = d0 + i;
        tile[i][tx] = (m < M_SIZE) ? W_m[(long)d * M_SIZE + m] : 0.0f;
    }
    __syncthreads();
    const int m0 = bx * 32;
    for (int i = ty; i < 32; i += 8) {
        const int mm = m0 + i;
        if (mm < M_SIZE) W_mT[(long)mm * D_MODEL + d0 + tx] = tile[tx][i];
    }
}

// ---------------------------------------------------------------------------
// Main kernel. Thread owns a FIXED float4 column slot c = tid&127 and
// grid-strides over rows s. W_t/b_t live in registers; per-row work is
// {broadcast t/marker (prefetched 1 ahead), 1 gather float4, FMA, NT store}.
// Waves cover 64 c-slots of one row -> t<0 branch is wave-uniform, stores
// fully coalesced.
// ---------------------------------------------------------------------------
__global__ void embed_kernel(const float* __restrict__ t,
                             const int* __restrict__ marker,
                             const float* __restrict__ W_mT,
                             const float* __restrict__ W_t,
                             const float* __restrict__ b_t,
                             float* __restrict__ out) {
    const int c = threadIdx.x & 127;              // float4 slot within row
    const int rowInBlock = threadIdx.x >> 7;      // 0 or 1 (256 threads = 2 rows)
    const int sStride = (int)gridDim.x * 2;

    const f32x4 w = reinterpret_cast<const f32x4*>(W_t)[c];
    const f32x4 b = reinterpret_cast<const f32x4*>(b_t)[c];
    f32x4* __restrict__ out4 = reinterpret_cast<f32x4*>(out);

    int s = (int)blockIdx.x * 2 + rowInBlock;
    if (s >= SEQ_LEN) return;

    // software pipeline: prefetch t/marker one row ahead
    float tv = t[s];
    int   m  = marker[s];

    while (true) {
        const int sn = s + sStride;
        float tv_n = 0.0f;
        int   m_n  = 0;
        if (sn < SEQ_LEN) {
            tv_n = t[sn];
            m_n  = marker[sn];
        }

        f32x4 o;
        if (tv < 0.0f) {
            o = (f32x4)(0.0f);
        } else {
            const f32x4 em =
                reinterpret_cast<const f32x4*>(W_mT + (size_t)m * D_MODEL)[c];
            o.x = BETA * em.x + (1.0f - BETA) * fmaf(tv, w.x, b.x);
            o.y = BETA * em.y + (1.0f - BETA) * fmaf(tv, w.y, b.y);
            o.z = BETA * em.z + (1.0f - BETA) * fmaf(tv, w.z, b.z);
            o.w = BETA * em.w + (1.0f - BETA) * fmaf(tv, w.w, b.w);
        }
        __builtin_nontemporal_store(o, out4 + (size_t)s * (D_MODEL / 4) + c);

        if (sn >= SEQ_LEN) break;
        s = sn; tv = tv_n; m = m_n;
    }
}

extern "C" void kernel_launch(void* const* d_in, const int* in_sizes, int n_in,
                              void* d_out, int out_size, void* d_ws, size_t ws_size,
                              hipStream_t stream) {
    const float* t      = (const float*)d_in[0];
    const int*   marker = (const int*)d_in[1];
    const float* W_m    = (const float*)d_in[2];
    const float* W_t    = (const float*)d_in[3];
    const float* b_t    = (const float*)d_in[4];
    float* out = (float*)d_out;

    float* W_mT = (float*)d_ws;
    (void)ws_size;

    dim3 tgrid((M_SIZE + 31) / 32, D_MODEL / 32);  // 32 x 16
    dim3 tblock(32, 8);
    transpose_wm_kernel<<<tgrid, tblock, 0, stream>>>(W_m, W_mT);

    // 2048 blocks x 256 threads: 2 rows/block-iter, 32 row-iters/thread.
    embed_kernel<<<2048, 256, 0, stream>>>(t, marker, W_mT, W_t, b_t, out);
}